// Round 1
// baseline (409.071 us; speedup 1.0000x reference)
//
#include <hip/hip_runtime.h>

#define N_ROWS 8192
#define DIMS   256
#define BM     64
#define BK     16

// ws layout:
// [0, 32768)        : float sq[8192]
// [32768, 33792)    : float colsum[256]        (zeroed each launch)
// [33792, ...)      : Scalars                  (zeroed each launch)
struct Scalars {
    double result;        // atomic double accumulator
    float  sumsq;         // atomic float accumulator
    unsigned int n0;      // atomic count of sub==0
    float  c2;            // -log2(e) / (16*bw)
    float  w0;            // +1/n0
    float  w1;            // -1/n1
};

// ---------------------------------------------------------------- K1: row/col stats
__global__ __launch_bounds__(256) void k1_rows(const float* __restrict__ x,
                                               const long long* __restrict__ sub,
                                               float* __restrict__ sq,
                                               float* __restrict__ colsum,
                                               Scalars* sc) {
    const int t    = threadIdx.x;
    const int lane = t & 63;
    const int wave = t >> 6;
    const int rowbase = blockIdx.x * 64 + wave * 16;

    float4 colacc = make_float4(0.f, 0.f, 0.f, 0.f);
    float  my_sumsq = 0.f;

    for (int r = 0; r < 16; ++r) {
        const int row = rowbase + r;
        const float4 v = ((const float4*)(x + (size_t)row * DIMS))[lane];
        colacc.x += v.x; colacc.y += v.y; colacc.z += v.z; colacc.w += v.w;
        float s = v.x * v.x + v.y * v.y + v.z * v.z + v.w * v.w;
        #pragma unroll
        for (int off = 32; off; off >>= 1) s += __shfl_down(s, off, 64);
        if (lane == 0) { sq[row] = s; my_sumsq += s; }
    }
    if (lane == 0) atomicAdd(&sc->sumsq, my_sumsq);

    const int d = lane * 4;
    atomicAdd(&colsum[d + 0], colacc.x);
    atomicAdd(&colsum[d + 1], colacc.y);
    atomicAdd(&colsum[d + 2], colacc.z);
    atomicAdd(&colsum[d + 3], colacc.w);

    if (wave == 0) {
        const int row = blockIdx.x * 64 + lane;
        const int v = (int)sub[row];
        unsigned long long mask = __ballot(v == 0);
        if (lane == 0) atomicAdd(&sc->n0, (unsigned int)__popcll(mask));
    }
}

// ---------------------------------------------------------------- K2: bandwidth & weights
__global__ __launch_bounds__(64) void k2_scalars(const float* __restrict__ colsum,
                                                 Scalars* sc) {
    const int lane = threadIdx.x;
    const float4 c = ((const float4*)colsum)[lane];
    float ss = c.x * c.x + c.y * c.y + c.z * c.z + c.w * c.w;
    #pragma unroll
    for (int off = 32; off; off >>= 1) ss += __shfl_down(ss, off, 64);
    if (lane == 0) {
        const double n = (double)N_ROWS;
        // sum(L2) = 2n*sum(sq) - 2*||colsum||^2  (diag clamp negligible: <1e-9 rel)
        const double sumL2 = 2.0 * n * (double)sc->sumsq - 2.0 * (double)ss;
        const double bw = sumL2 / (n * n - n) / 4.0;   // / KERNEL_MUL^(KERNEL_NUM/2)
        sc->c2 = (float)(-1.4426950408889634 / (16.0 * bw));
        const double n0 = (double)sc->n0;
        const double n1 = n - n0;
        sc->w0 = (float)( 1.0 / n0);
        sc->w1 = (float)(-1.0 / n1);
    }
}

// ---------------------------------------------------------------- K3: fused Gram + kernel + reduce
__global__ __launch_bounds__(256) void k3_mmd(const float* __restrict__ x,
                                              const long long* __restrict__ sub,
                                              const float* __restrict__ sq,
                                              Scalars* sc) {
    const int bi = blockIdx.y;   // row tile
    const int bj = blockIdx.x;   // col tile
    if (bj < bi) return;         // upper triangle only (uniform exit)

    __shared__ float As[BK][BM];
    __shared__ float Bs[BK][BM];
    __shared__ float red[256];

    const int t  = threadIdx.x;
    const int tx = t & 15;       // col group (4 cols)
    const int ty = t >> 4;       // row group (4 rows)

    float acc[4][4];
    #pragma unroll
    for (int r = 0; r < 4; ++r)
        #pragma unroll
        for (int c = 0; c < 4; ++c) acc[r][c] = 0.f;

    const int lrow = t >> 2;          // 0..63
    const int lcol = (t & 3) * 4;     // 0,4,8,12
    const float* Arow = x + (size_t)(bi * 64 + lrow) * DIMS;
    const float* Brow = x + (size_t)(bj * 64 + lrow) * DIMS;

    for (int kc = 0; kc < DIMS; kc += BK) {
        const float4 av = *(const float4*)(Arow + kc + lcol);
        const float4 bv = *(const float4*)(Brow + kc + lcol);
        __syncthreads();
        As[lcol + 0][lrow] = av.x; As[lcol + 1][lrow] = av.y;
        As[lcol + 2][lrow] = av.z; As[lcol + 3][lrow] = av.w;
        Bs[lcol + 0][lrow] = bv.x; Bs[lcol + 1][lrow] = bv.y;
        Bs[lcol + 2][lrow] = bv.z; Bs[lcol + 3][lrow] = bv.w;
        __syncthreads();
        #pragma unroll
        for (int kk = 0; kk < BK; ++kk) {
            const float4 a = *(const float4*)&As[kk][ty * 4];
            const float4 b = *(const float4*)&Bs[kk][tx * 4];
            acc[0][0] += a.x * b.x; acc[0][1] += a.x * b.y; acc[0][2] += a.x * b.z; acc[0][3] += a.x * b.w;
            acc[1][0] += a.y * b.x; acc[1][1] += a.y * b.y; acc[1][2] += a.y * b.z; acc[1][3] += a.y * b.w;
            acc[2][0] += a.z * b.x; acc[2][1] += a.z * b.y; acc[2][2] += a.z * b.z; acc[2][3] += a.z * b.w;
            acc[3][0] += a.w * b.x; acc[3][1] += a.w * b.y; acc[3][2] += a.w * b.z; acc[3][3] += a.w * b.w;
        }
    }

    // epilogue: L2 -> multi-scale kernel -> weighted partial sum
    const float c2 = sc->c2, w0 = sc->w0, w1 = sc->w1;
    const int gI = bi * 64 + ty * 4;
    const int gJ = bj * 64 + tx * 4;
    float sqI[4], sqJ[4], wI[4], wJ[4];
    #pragma unroll
    for (int r = 0; r < 4; ++r) {
        sqI[r] = sq[gI + r];
        wI[r]  = ((int)sub[gI + r] == 0) ? w0 : w1;
        sqJ[r] = sq[gJ + r];
        wJ[r]  = ((int)sub[gJ + r] == 0) ? w0 : w1;
    }

    float part = 0.f;
    const bool offdiag = (bi < bj);
    #pragma unroll
    for (int r = 0; r < 4; ++r) {
        #pragma unroll
        for (int c = 0; c < 4; ++c) {
            const int I = gI + r, J = gJ + c;
            float l2 = sqI[r] + sqJ[c] - 2.f * acc[r][c];
            l2 = fmaxf(l2, 0.f);
            const float tt  = exp2f(l2 * c2);           // exp(-L2/(16*bw))
            const float t2  = tt * tt;
            const float t4  = t2 * t2;
            const float t8  = t4 * t4;
            const float t16 = t8 * t8;
            const float K   = tt + t2 + t4 + t8 + t16;
            float f;
            if (offdiag) f = 2.f;
            else         f = (I < J) ? 2.f : ((I == J) ? 1.f : 0.f);
            part += f * wI[r] * wJ[c] * K;
        }
    }

    red[t] = part;
    __syncthreads();
    #pragma unroll
    for (int s = 128; s; s >>= 1) {
        if (t < s) red[t] += red[t + s];
        __syncthreads();
    }
    if (t == 0) atomicAdd(&sc->result, (double)red[0]);
}

// ---------------------------------------------------------------- K4: emit scalar
__global__ void k4_write(const Scalars* sc, float* out) {
    if (threadIdx.x == 0) out[0] = (float)sc->result;
}

extern "C" void kernel_launch(void* const* d_in, const int* in_sizes, int n_in,
                              void* d_out, int out_size, void* d_ws, size_t ws_size,
                              hipStream_t stream) {
    const long long* sub = (const long long*)d_in[0];   // subggroup int64 (N,1)
    const float*     x   = (const float*)d_in[1];       // outputs fp32 (N,256)
    float* out = (float*)d_out;

    char* ws = (char*)d_ws;
    float*   sq     = (float*)ws;
    float*   colsum = (float*)(ws + 32768);
    Scalars* sc     = (Scalars*)(ws + 33792);

    // zero the accumulators (colsum + scalars); sq is fully overwritten
    hipMemsetAsync(ws + 32768, 0, 2048, stream);

    k1_rows<<<N_ROWS / 64, 256, 0, stream>>>(x, sub, sq, colsum, sc);
    k2_scalars<<<1, 64, 0, stream>>>(colsum, sc);

    dim3 g3(N_ROWS / BM, N_ROWS / BM);
    k3_mmd<<<g3, 256, 0, stream>>>(x, sub, sq, sc);

    k4_write<<<1, 64, 0, stream>>>(sc, out);
}